// Round 16
// baseline (2157.602 us; speedup 1.0000x reference)
//
#include <hip/hip_runtime.h>
#include <hip/hip_bf16.h>

namespace {

constexpr int cT   = 1024;
constexpr int cD   = 768;
constexpr int cH   = 8;
constexpr int cHD  = 96;
constexpr int cM   = 10;
constexpr int cDff = 3072;
constexpr int cV   = 32000;
constexpr int cTD  = cT * cD;
constexpr float cEps = 1e-6f;

// slot element offsets (slot = one layer's 6 matrices)
constexpr long oWQ = 0;
constexpr long oWK = 589824;
constexpr long oWV = 2L * 589824;
constexpr long oWO = 3L * 589824;
constexpr long oFC = 4L * 589824;
constexpr long oPR = 4L * 589824 + 2359296;
constexpr long cWTOT = 4L * 589824 + 2L * 2359296;   // 7077888
constexpr int cConvBlocks = (int)(cWTOT / 8 / 256);  // 3456
constexpr long cLM = (long)cV * cD;                  // 24576000
constexpr int cConvLMBlocks = (int)(cLM / 8 / 256);  // 12000

typedef __attribute__((ext_vector_type(8))) short short8;
typedef __attribute__((ext_vector_type(4))) float f32x4;

__device__ inline short bf16r(float f) {
  union { float f; unsigned u; } x{f};
  unsigned r = (x.u + 0x7FFF + ((x.u >> 16) & 1)) >> 16;
  return (short)r;
}

__device__ inline float bf2f(short s) {
  union { unsigned u; float f; } x;
  x.u = ((unsigned)(unsigned short)s) << 16;
  return x.f;
}

__device__ inline short8 cvt8(const float* __restrict__ p) {
  float4 a0 = *(const float4*)p;
  float4 a1 = *(const float4*)(p + 4);
  short8 sv;
  sv[0]=bf16r(a0.x); sv[1]=bf16r(a0.y); sv[2]=bf16r(a0.z); sv[3]=bf16r(a0.w);
  sv[4]=bf16r(a1.x); sv[5]=bf16r(a1.y); sv[6]=bf16r(a1.z); sv[7]=bf16r(a1.w);
  return sv;
}

// convert one 2048-element chunk of a 6-matrix slot
__device__ inline void conv6(const float* s0, const float* s1, const float* s2,
    const float* s3, const float* s4, const float* s5, long cu,
    short* __restrict__ dst, long cb) {
  long e = (cb * 256 + threadIdx.x) * 8;
  const float* src;
  if (e < oWK)      src = s0 + cu * 589824L + e;
  else if (e < oWV) src = s1 + cu * 589824L + (e - oWK);
  else if (e < oWO) src = s2 + cu * 589824L + (e - oWV);
  else if (e < oFC) src = s3 + cu * 589824L + (e - oWO);
  else if (e < oPR) src = s4 + cu * 2359296L + (e - oFC);
  else              src = s5 + cu * 2359296L + (e - oPR);
  *(short8*)(dst + e) = cvt8(src);
}

// ---------------- state / misc ----------------

__global__ void init_state_k(int* cur, int* done, float* cnt, float* feat) {
  if (threadIdx.x == 0) { *cur = 0; *done = 0; *cnt = 0.0f; }
  for (int d = threadIdx.x; d < cD; d += 256) feat[d] = 0.f;
}

__global__ void rope_pre_k(float* __restrict__ cosb, float* __restrict__ sinb) {
  int idx = blockIdx.x * blockDim.x + threadIdx.x;
  if (idx >= cT * 48) return;
  int t = idx / 48, j = idx % 48;
  float th = 0.0f;
  if (j < 24) th = (float)t * powf(1.0f / 1024.0f, (float)j / 23.0f);
  cosb[idx] = cosf(th);
  sinb[idx] = sinf(th);
}

// embed rms + fused IN-weight conversion (blocks >= cT)
__global__ __launch_bounds__(256) void embed_rms_k(const int* __restrict__ tok,
    const float* __restrict__ ew, const float* __restrict__ vw,
    float* __restrict__ x0, float* __restrict__ ve,
    const float* iq, const float* ik, const float* iv, const float* io,
    const float* if_, const float* ip, short* __restrict__ cdst) {
  const int b = blockIdx.x;
  if (b >= cT) {
    conv6(iq, ik, iv, io, if_, ip, 0, cdst, b - cT);
    return;
  }
  int t = b;
  int tk = tok[t];
  const float* er = ew + (size_t)tk * cD;
  const float* vr = vw + (size_t)tk * cD;
  __shared__ float red[256];
  float s = 0.f;
  for (int d = threadIdx.x; d < cD; d += 256) { float e = er[d]; s += e * e; }
  red[threadIdx.x] = s; __syncthreads();
  for (int st = 128; st; st >>= 1) { if (threadIdx.x < st) red[threadIdx.x] += red[threadIdx.x + st]; __syncthreads(); }
  float sc = rsqrtf(red[0] / cD + cEps);
  for (int d = threadIdx.x; d < cD; d += 256) {
    x0[(size_t)t * cD + d] = er[d] * sc;
    ve[(size_t)t * cD + d] = vr[d];
  }
}

// rms over rows -> bf16 output (used pre-lm_head)
__global__ __launch_bounds__(256) void rms_rows_bf(const float* __restrict__ in,
    short* __restrict__ out, const int* done) {
  if (done && *done) return;
  int t = blockIdx.x;
  const float* r = in + (size_t)t * cD;
  __shared__ float red[256];
  float s = 0.f;
  for (int d = threadIdx.x; d < cD; d += 256) { float v = r[d]; s += v * v; }
  red[threadIdx.x] = s; __syncthreads();
  for (int st = 128; st; st >>= 1) { if (threadIdx.x < st) red[threadIdx.x] += red[threadIdx.x + st]; __syncthreads(); }
  float sc = rsqrtf(red[0] / cD + cEps);
  short* o = out + (size_t)t * cD;
  for (int d = threadIdx.x; d < cD; d += 256) o[d] = bf16r(r[d] * sc);
}

// rms + rsum zero (in/out layers)
__global__ __launch_bounds__(256) void rms_pre_k(const float* __restrict__ in,
    short* __restrict__ out, float* __restrict__ rsum, const int* done) {
  if (done && *done) return;
  int t = blockIdx.x;
  const float* r = in + (size_t)t * cD;
  __shared__ float red[256];
  float s = 0.f;
  for (int d = threadIdx.x; d < cD; d += 256) { float v = r[d]; s += v * v; }
  red[threadIdx.x] = s; __syncthreads();
  for (int st = 128; st; st >>= 1) { if (threadIdx.x < st) red[threadIdx.x] += red[threadIdx.x + st]; __syncthreads(); }
  float sc = rsqrtf(red[0] / cD + cEps);
  short* o = out + (size_t)t * cD;
  for (int d = threadIdx.x; d < cD; d += 256) o[d] = bf16r(r[d] * sc);
  if (threadIdx.x == 0) rsum[t] = 0.f;
}

__global__ void axpy_lam_k(const float* __restrict__ lam, const float* __restrict__ a,
                           const float* __restrict__ b, float* __restrict__ o, int n) {
  int i = blockIdx.x * 256 + threadIdx.x;
  if (i < n) o[i] = lam[0] * a[i] + lam[1] * b[i];
}

// ---------------- fix_pre: corrective convert (if speculation wrong) + rms ---------

__global__ __launch_bounds__(256) void fix_pre_k(const float* __restrict__ s0,
    const float* __restrict__ s1, const float* __restrict__ s2, const float* __restrict__ s3,
    const float* __restrict__ s4, const float* __restrict__ s5, short* __restrict__ dst,
    const int* __restrict__ cur, const int* __restrict__ done, int expected,
    const float* __restrict__ xin, short* __restrict__ xnbf, float* __restrict__ rsum) {
  if (done && *done) return;
  const int b = blockIdx.x;
  if (b < cConvBlocks) {
    const int c = cur ? *cur : 0;
    if (c == expected) return;          // speculation was right -> nothing to do
    conv6(s0, s1, s2, s3, s4, s5, c, dst, b);
  } else {
    const int t = b - cConvBlocks;
    const float* r = xin + (size_t)t * cD;
    __shared__ float red[256];
    float s = 0.f;
    for (int d = threadIdx.x; d < cD; d += 256) { float v = r[d]; s += v * v; }
    red[threadIdx.x] = s; __syncthreads();
    for (int st = 128; st; st >>= 1) { if (threadIdx.x < st) red[threadIdx.x] += red[threadIdx.x + st]; __syncthreads(); }
    float sc = rsqrtf(red[0] / cD + cEps);
    short* o = xnbf + (size_t)t * cD;
    for (int d = threadIdx.x; d < cD; d += 256) o[d] = bf16r(r[d] * sc);
    if (threadIdx.x == 0) rsum[t] = 0.f;
  }
}

// ---------------- QKV GEMM with fused per-head RMS + RoPE / lam-scale -------------

__global__ __launch_bounds__(256) void qkv_k(const short* __restrict__ A,
    const short* __restrict__ Wb,
    short* __restrict__ qo, short* __restrict__ ko, short* __restrict__ vo,
    const int* __restrict__ done, const float* __restrict__ lamb,
    const int* __restrict__ cur, const float* __restrict__ vep,
    const float* __restrict__ cosb, const float* __restrict__ sinb) {
  if (done && *done) return;
  const int z = blockIdx.z;
  const short* W = Wb + (long)z * 589824L;
  const int h  = blockIdx.x;
  const int bm = blockIdx.y * 64;
  __shared__ short As[2][64][40];
  __shared__ short Bs[2][96][40];
  const int tid = threadIdx.x;
  const int w = tid >> 6, lane = tid & 63;
  const int fr = lane & 15, fg = lane >> 4;
  const int ar = tid >> 2, ac2 = (tid & 3) << 3;
  const int br1 = (256 + tid) >> 2, bc1 = ((256 + tid) & 3) << 3;

  short8 aN, bN0, bN1;
  aN  = *(const short8*)(A + (size_t)(bm + ar) * cD + ac2);
  bN0 = *(const short8*)(W + (size_t)(h * cHD + ar) * cD + ac2);
  if (tid < 128) bN1 = *(const short8*)(W + (size_t)(h * cHD + br1) * cD + bc1);
  *(short8*)&As[0][ar][ac2] = aN;
  *(short8*)&Bs[0][ar][ac2] = bN0;
  if (tid < 128) *(short8*)&Bs[0][br1][bc1] = bN1;
  __syncthreads();

  f32x4 acc[6] = {};
  int cb = 0;
  for (int kt = 0; kt < cD; kt += 32) {
    const int ktn = kt + 32;
    const bool hn = ktn < cD;
    if (hn) {
      aN  = *(const short8*)(A + (size_t)(bm + ar) * cD + ktn + ac2);
      bN0 = *(const short8*)(W + (size_t)(h * cHD + ar) * cD + ktn + ac2);
      if (tid < 128) bN1 = *(const short8*)(W + (size_t)(h * cHD + br1) * cD + ktn + bc1);
    }
    short8 af = *(const short8*)&As[cb][w * 16 + fr][fg * 8];
#pragma unroll
    for (int n = 0; n < 6; ++n) {
      short8 bf = *(const short8*)&Bs[cb][n * 16 + fr][fg * 8];
      acc[n] = __builtin_amdgcn_mfma_f32_16x16x32_bf16(af, bf, acc[n], 0, 0, 0);
    }
    if (hn) {
      *(short8*)&As[cb ^ 1][ar][ac2] = aN;
      *(short8*)&Bs[cb ^ 1][ar][ac2] = bN0;
      if (tid < 128) *(short8*)&Bs[cb ^ 1][br1][bc1] = bN1;
    }
    __syncthreads();
    cb ^= 1;
  }

  const int t0 = bm + w * 16 + fg * 4;
  if (z < 2) {
    float scl[4];
#pragma unroll
    for (int r = 0; r < 4; ++r) {
      float s = 0.f;
#pragma unroll
      for (int n = 0; n < 6; ++n) s += acc[n][r] * acc[n][r];
#pragma unroll
      for (int mm = 1; mm < 16; mm <<= 1) s += __shfl_xor(s, mm, 64);
      scl[r] = rsqrtf(s * (1.0f / 96.0f) + cEps);
    }
    short* C = (z == 0 ? qo : ko);
#pragma unroll
    for (int r = 0; r < 4; ++r) {
      int t = t0 + r;
      short* orow = C + (size_t)t * cD + h * cHD;
#pragma unroll
      for (int n = 0; n < 3; ++n) {
        int j = n * 16 + fr;
        float c = cosb[t * 48 + j], sn = sinb[t * 48 + j];
        float x1 = acc[n][r] * scl[r], x2 = acc[n + 3][r] * scl[r];
        orow[j]      = bf16r(x1 * c + x2 * sn);
        orow[j + 48] = bf16r(-x1 * sn + x2 * c);
      }
    }
  } else {
    int cu = cur ? *cur : 0;
    float l0 = lamb[2 * cu], l1 = lamb[2 * cu + 1];
#pragma unroll
    for (int r = 0; r < 4; ++r) {
      int t = t0 + r;
#pragma unroll
      for (int n = 0; n < 6; ++n) {
        float val = l0 * acc[n][r];
        if (vep) val += l1 * vep[(size_t)t * cD + h * cHD + n * 16 + fr];
        vo[(size_t)t * cD + h * cHD + n * 16 + fr] = bf16r(val);
      }
    }
  }
}

// ---------------- flash attention (windowed causal, bf16 in/out, pipelined) -------

__global__ __launch_bounds__(256) void attn_f(const short* __restrict__ q,
    const short* __restrict__ k, const short* __restrict__ v, short* __restrict__ o,
    const int* __restrict__ wbp, const int* done) {
  if (done && *done) return;
  const int qb = blockIdx.x;
  const int h  = blockIdx.y;
  const int q0 = qb * 64;
  const int qb128 = q0 >> 7;
  const int wb = *wbp;
  int kb_lo = qb128 - wb + 1; if (kb_lo < 0) kb_lo = 0;

  __shared__ short Ksh[128][136];
  __shared__ short Vt[96][136];

  const int tid  = threadIdx.x;
  const int w    = tid >> 6;
  const int lane = tid & 63;
  const int fr   = lane & 15;
  const int fg   = lane >> 4;

  short8 qf[3];
  {
    const short* qrow = q + (size_t)(q0 + w * 16 + fr) * cD + h * cHD;
#pragma unroll
    for (int ks = 0; ks < 3; ++ks) qf[ks] = *(const short8*)(qrow + ks * 32 + fg * 8);
  }

  short8 rK[6], rV[6];
  auto issue = [&](int kb) {
    const int key0 = kb * 128;
#pragma unroll
    for (int c = 0; c < 6; ++c) {
      int idx = c * 256 + tid;
      int row = idx / 12, colc = (idx % 12) * 8;
      rK[c] = *(const short8*)(k + (size_t)(key0 + row) * cD + h * cHD + colc);
      rV[c] = *(const short8*)(v + (size_t)(key0 + row) * cD + h * cHD + colc);
    }
  };

  f32x4 accO[6] = {};
  float mrun[4], lrun[4];
#pragma unroll
  for (int r = 0; r < 4; ++r) { mrun[r] = -1e30f; lrun[r] = 0.f; }

  issue(kb_lo);
  for (int kb = kb_lo; kb <= qb128; ++kb) {
    __syncthreads();
#pragma unroll
    for (int c = 0; c < 6; ++c) {
      int idx = c * 256 + tid;
      int row = idx / 12, colc = (idx % 12) * 8;
      *(short8*)&Ksh[row][colc] = rK[c];
      short8 vv = rV[c];
#pragma unroll
      for (int i = 0; i < 8; ++i) Vt[colc + i][row] = vv[i];
    }
    __syncthreads();
    if (kb < qb128) issue(kb + 1);

    const int key0 = kb * 128;
    f32x4 s[8];
#pragma unroll
    for (int n = 0; n < 8; ++n) s[n] = (f32x4){0.f, 0.f, 0.f, 0.f};
#pragma unroll
    for (int ks = 0; ks < 3; ++ks) {
#pragma unroll
      for (int n = 0; n < 8; ++n) {
        short8 kf = *(const short8*)&Ksh[n * 16 + fr][ks * 32 + fg * 8];
        s[n] = __builtin_amdgcn_mfma_f32_16x16x32_bf16(qf[ks], kf, s[n], 0, 0, 0);
      }
    }

    float pmax[4] = {-1e30f, -1e30f, -1e30f, -1e30f};
#pragma unroll
    for (int n = 0; n < 8; ++n)
#pragma unroll
      for (int r = 0; r < 4; ++r) {
        float val = s[n][r] * 0.10206207261596577f;
        int key  = key0 + n * 16 + fr;
        int qrow = q0 + w * 16 + fg * 4 + r;
        if (key > qrow) val = -1e30f;
        s[n][r] = val;
        pmax[r] = fmaxf(pmax[r], val);
      }
#pragma unroll
    for (int mm = 1; mm < 16; mm <<= 1)
#pragma unroll
      for (int r = 0; r < 4; ++r) pmax[r] = fmaxf(pmax[r], __shfl_xor(pmax[r], mm, 64));
    float alpha[4], psum[4];
#pragma unroll
    for (int r = 0; r < 4; ++r) {
      float mn = fmaxf(mrun[r], pmax[r]);
      alpha[r] = __expf(mrun[r] - mn);
      mrun[r] = mn;
      psum[r] = 0.f;
    }
#pragma unroll
    for (int n = 0; n < 8; ++n)
#pragma unroll
      for (int r = 0; r < 4; ++r) {
        float p = __expf(s[n][r] - mrun[r]);
        s[n][r] = p;
        psum[r] += p;
      }
#pragma unroll
    for (int mm = 1; mm < 16; mm <<= 1)
#pragma unroll
      for (int r = 0; r < 4; ++r) psum[r] += __shfl_xor(psum[r], mm, 64);
#pragma unroll
    for (int r = 0; r < 4; ++r) lrun[r] = lrun[r] * alpha[r] + psum[r];
#pragma unroll
    for (int n = 0; n < 6; ++n) {
      f32x4 t = accO[n];
#pragma unroll
      for (int r = 0; r < 4; ++r) t[r] *= alpha[r];
      accO[n] = t;
    }

    __syncthreads();
#pragma unroll
    for (int n = 0; n < 8; ++n)
#pragma unroll
      for (int r = 0; r < 4; ++r)
        Ksh[w * 16 + fg * 4 + r][n * 16 + fr] = bf16r(s[n][r]);
    __syncthreads();

#pragma unroll
    for (int ks = 0; ks < 4; ++ks) {
      short8 pf = *(const short8*)&Ksh[w * 16 + fr][ks * 32 + fg * 8];
#pragma unroll
      for (int n = 0; n < 6; ++n) {
        short8 vf = *(const short8*)&Vt[n * 16 + fr][ks * 32 + fg * 8];
        accO[n] = __builtin_amdgcn_mfma_f32_16x16x32_bf16(pf, vf, accO[n], 0, 0, 0);
      }
    }
  }

#pragma unroll
  for (int r = 0; r < 4; ++r) {
    float inv = 1.0f / lrun[r];
    int t = q0 + w * 16 + fg * 4 + r;
#pragma unroll
    for (int n = 0; n < 6; ++n)
      o[(size_t)t * cD + h * cHD + n * 16 + fr] = bf16r(accO[n][r] * inv);
  }
}

// ---------------- 64x64-tile GEMM, double-buffered -------------------------------

template <int EPI, typename OT>
__global__ __launch_bounds__(256) void gemm64_k(const short* __restrict__ A,
    const short* __restrict__ W, OT* __restrict__ C, const int* __restrict__ done,
    const float* __restrict__ res, float* __restrict__ rsum, int ld, int kn, int N) {
  if (done && *done) return;
  const int bm = blockIdx.y * 64;
  const int bn = blockIdx.x * 64;
  const int k0 = blockIdx.z * kn;
  __shared__ short As[2][64][40];
  __shared__ short Bs[2][64][40];
  const int tid = threadIdx.x;
  const int wid = tid >> 6, lane = tid & 63;
  const int wr = wid >> 1, wc = wid & 1;
  const int fr = lane & 15, fg = lane >> 4;
  const int ar = tid >> 2, ac = (tid & 3) << 3;

  short8 aN = *(const short8*)(A + (size_t)(bm + ar) * ld + k0 + ac);
  short8 bN = *(const short8*)(W + (size_t)(bn + ar) * ld + k0 + ac);
  *(short8*)&As[0][ar][ac] = aN;
  *(short8*)&Bs[0][ar][ac] = bN;
  __syncthreads();

  f32x4 acc[2][2] = {};
  int cb = 0;
  for (int kt = 0; kt < kn; kt += 32) {
    const int ktn = kt + 32;
    const bool hn = ktn < kn;
    if (hn) {
      aN = *(const short8*)(A + (size_t)(bm + ar) * ld + k0 + ktn + ac);
      bN = *(const short8*)(W + (size_t)(bn + ar) * ld + k0 + ktn + ac);
    }
    short8 af[2], bfv[2];
#pragma unroll
    for (int m = 0; m < 2; ++m) af[m] = *(const short8*)&As[cb][wr * 32 + m * 16 + fr][fg * 8];
#pragma unroll
    for (int n = 0; n < 2; ++n) bfv[n] = *(const short8*)&Bs[cb][wc * 32 + n * 16 + fr][fg * 8];
#pragma unroll
    for (int m = 0; m < 2; ++m)
#pragma unroll
      for (int n = 0; n < 2; ++n)
        acc[m][n] = __builtin_amdgcn_mfma_f32_16x16x32_bf16(af[m], bfv[n], acc[m][n], 0, 0, 0);
    if (hn) {
      *(short8*)&As[cb ^ 1][ar][ac] = aN;
      *(short8*)&Bs[cb ^ 1][ar][ac] = bN;
    }
    __syncthreads();
    cb ^= 1;
  }
#pragma unroll
  for (int m = 0; m < 2; ++m)
#pragma unroll
    for (int r = 0; r < 4; ++r) {
      const int row = bm + wr * 32 + m * 16 + fg * 4 + r;
      float p = 0.f;
#pragma unroll
      for (int n = 0; n < 2; ++n) {
        const int col = bn + wc * 32 + n * 16 + fr;
        float val = acc[m][n][r];
        if constexpr (EPI == 1) {
          val += res[(size_t)row * N + col];
          C[(size_t)row * N + col] = val;
          p += val * val;
        } else {
          C[(size_t)blockIdx.z * cTD + (size_t)row * N + col] = (OT)bf16r(val);
        }
      }
      if constexpr (EPI == 1) {
#pragma unroll
        for (int mm = 1; mm < 16; mm <<= 1) p += __shfl_xor(p, mm, 64);
        if (fr == 0) atomicAdd(&rsum[row], p);
      }
    }
}

// ---------------- fc GEMM with fused RMS on A ------------------------------------

__global__ __launch_bounds__(256) void mgemm_fc_k(const float* __restrict__ Ay,
    const float* __restrict__ rsum, const short* __restrict__ W, short* __restrict__ C,
    const int* __restrict__ done, int K, int N) {
  if (done && *done) return;
  const int bm = blockIdx.y * 64;
  const int bn = blockIdx.x * 128;
  __shared__ short As[2][64][40];
  __shared__ short Bs[2][128][40];
  const int tid = threadIdx.x;
  const int wid = tid >> 6, lane = tid & 63;
  const int wr = wid >> 1, wc = wid & 1;
  const int fr = lane & 15, fg = lane >> 4;
  const int ar = tid >> 2, ac = (tid & 3) << 3;
  const int br1 = (256 + tid) >> 2, bc1 = ((256 + tid) & 3) << 3;

  const float ascl = rsqrtf(rsum[bm + ar] * (1.0f / cD) + cEps);
  const float* arow = Ay + (size_t)(bm + ar) * K;

  auto loadA = [&](int kt) -> short8 {
    float4 a0 = *(const float4*)(arow + kt + ac);
    float4 a1 = *(const float4*)(arow + kt + ac + 4);
    short8 sv;
    sv[0]=bf16r(a0.x*ascl); sv[1]=bf16r(a0.y*ascl); sv[2]=bf16r(a0.z*ascl); sv[3]=bf16r(a0.w*ascl);
    sv[4]=bf16r(a1.x*ascl); sv[5]=bf16r(a1.y*ascl); sv[6]=bf16r(a1.z*ascl); sv[7]=bf16r(a1.w*ascl);
    return sv;
  };

  short8 aN, bN0, bN1;
  aN  = loadA(0);
  bN0 = *(const short8*)(W + (size_t)(bn + ar) * K + ac);
  bN1 = *(const short8*)(W + (size_t)(bn + br1) * K + bc1);
  *(short8*)&As[0][ar][ac] = aN;
  *(short8*)&Bs[0][ar][ac] = bN0;
  *(short8*)&Bs[0][br1][bc1] = bN1;
  __syncthreads();

  f32x4 acc[2][4] = {};
  int cb = 0;
  for (int kt = 0; kt < K; kt += 32) {
    const int ktn = kt + 32;
    const bool hn = ktn < K;
    if (hn) {
      aN  = loadA(ktn);
      bN0 = *(const short8*)(W + (size_t)(bn + ar) * K + ktn + ac);
      bN1 = *(const short8*)(W + (size_t)(bn + br1) * K + ktn + bc1);
    }
    short8 af[2], bfv[4];
#pragma unroll
    for (int m = 0; m < 2; ++m) af[m] = *(const short8*)&As[cb][wr * 32 + m * 16 + fr][fg * 8];
#pragma unroll
    for (int n = 0; n < 4; ++n) bfv[n] = *(const short8*)&Bs[cb][wc * 64 + n * 16 + fr][fg * 8];
#pragma unroll
    for (int m = 0; m < 2; ++m)
#pragma unroll
      for (int n = 0; n < 4; ++n)
        acc[m][n] = __builtin_amdgcn_mfma_f32_16x16x32_bf16(af[m], bfv[n], acc[m][n], 0, 0, 0);
    if (hn) {
      *(short8*)&As[cb ^ 1][ar][ac] = aN;
      *(short8*)&Bs[cb ^ 1][ar][ac] = bN0;
      *(short8*)&Bs[cb ^ 1][br1][bc1] = bN1;
    }
    __syncthreads();
    cb ^= 1;
  }
#pragma unroll
  for (int m = 0; m < 2; ++m)
#pragma unroll
    for (int n = 0; n < 4; ++n)
#pragma unroll
      for (int r = 0; r < 4; ++r) {
        int row = bm + wr * 32 + m * 16 + fg * 4 + r;
        int col = bn + wc * 64 + n * 16 + fr;
        float val = acc[m][n][r];
        val = fmaxf(val, 0.f); val = val * val;
        C[(size_t)row * N + col] = bf16r(val);
      }
}

// ---------------- reduce + residual + commit + feat + fused speculative convert ----
// main blocks: bx < 24 (cols) x by (row chunks). conv blocks: bx >= 24.
// cmode: 0 = 6-array slot (cs0..cs5, cexp), 1 = single lm array (csLM).

__global__ __launch_bounds__(256) void reduce_k(const short* __restrict__ pb,
    float* __restrict__ y, float* __restrict__ x, float* __restrict__ feat,
    const int* done,
    const float* cs0, const float* cs1, const float* cs2,
    const float* cs3, const float* cs4, const float* cs5,
    const float* csLM, long cexp, short* __restrict__ cdst,
    int cmode, int ungated) {
  if (blockIdx.x >= cD / 32) {
    if (!ungated && done && *done) return;
    long cb = (long)(blockIdx.x - cD / 32) * gridDim.y + blockIdx.y;
    if (cmode == 0) {
      if (cb < cConvBlocks) conv6(cs0, cs1, cs2, cs3, cs4, cs5, cexp, cdst, cb);
    } else {
      if (cb < cConvLMBlocks) {
        long e = (cb * 256 + threadIdx.x) * 8;
        *(short8*)(cdst + e) = cvt8(csLM + e);
      }
    }
    return;
  }
  if (done && *done) return;
  __shared__ float red[256];
  const int d = blockIdx.x * 32 + (threadIdx.x & 31);
  const int tc = threadIdx.x >> 5;
  const int t0 = blockIdx.y * 128 + tc * 16;
  float s = 0.f;
  for (int t = t0; t < t0 + 16; ++t) {
    size_t i = (size_t)t * cD + d;
    float v = y[i];
#pragma unroll
    for (int z = 0; z < 4; ++z) v += bf2f(pb[(size_t)z * cTD + i]);
    y[i] = v;
    if (x) x[i] = v;
    s += v;
  }
  if (feat) {
    red[threadIdx.x] = s; __syncthreads();
    if (threadIdx.x < 32) {
      float tot = 0.f;
#pragma unroll
      for (int c = 0; c < 8; ++c) tot += red[c * 32 + threadIdx.x];
      atomicAdd(&feat[d], tot * (1.0f / cT));
    }
  }
}

// ---------------- router (single block; zeroes feat for next iteration) ------------

__global__ void router_step_k(float* __restrict__ feat, const float* __restrict__ rw,
    const float* __restrict__ rb, const float* __restrict__ gu, int iter,
    const int* __restrict__ mbcp, int* cur, int* done, float* cnt) {
  if (*done) return;
  __shared__ float lg[cM + 1];
  const int tid = threadIdx.x;   // 64 threads
  const int c = *cur;
  const float mbc = (float)(*mbcp);
  const float cn = *cnt;
  for (int j = 0; j < cM + 1; ++j) {
    const float* w = rw + ((size_t)c * (cM + 1) + j) * (cD + 2);
    float s = 0.f;
    for (int d = tid; d < cD; d += 64) s += feat[d] * w[d];
#pragma unroll
    for (int mm = 32; mm; mm >>= 1) s += __shfl_xor(s, mm, 64);
    if (tid == 0) {
      s += cn * w[cD] + mbc * w[cD + 1] + rb[c * (cM + 1) + j];
      float u = gu[iter * (cM + 1) + j];
      float inner = -logf(u + 1e-10f) + 1e-10f;
      lg[j] = s - logf(inner);
    }
  }
  __syncthreads();
  for (int d = tid; d < cD; d += 64) feat[d] = 0.f;
  if (tid == 0) {
    int nxt = 0; float best = lg[0];
    for (int j = 1; j < cM + 1; ++j) if (lg[j] > best) { best = lg[j]; nxt = j; }
    float nc = cn + 1.0f;
    int ex = (nxt == cM) || (nc >= mbc);
    *cnt = nc;
    if (ex) *done = 1; else *cur = nxt;
  }
}

// ---------------- lm_head GEMM: 128x128 tile, 256 threads, dbuf, XCD swizzle --------

__global__ __launch_bounds__(256) void gemm_lm_k(const short* __restrict__ A,
    const short* __restrict__ W, float* __restrict__ C) {
  const int nwg = (cV / 128) * (cT / 128);        // 2000
  const int cpx = nwg / 8;                        // 250
  const int swz = (blockIdx.x % 8) * cpx + blockIdx.x / 8;
  const int bm = (swz & 7) * 128;
  const int bn = (swz >> 3) * 128;
  __shared__ short As[2][128][40];
  __shared__ short Bs[2][128][40];
  const int tid = threadIdx.x;
  const int wid = tid >> 6, lane = tid & 63;
  const int wr = wid >> 1, wc = wid & 1;
  const int fr = lane & 15, fg = lane >> 4;
  const int r0 = tid >> 2, c0 = (tid & 3) << 3;
  const int r1 = (256 + tid) >> 2, c1 = ((256 + tid) & 3) << 3;

  short8 aN0, aN1, bN0, bN1;
  aN0 = *(const short8*)(A + (size_t)(bm + r0) * cD + c0);
  aN1 = *(const short8*)(A + (size_t)(bm + r1) * cD + c1);
  bN0 = *(const short8*)(W + (size_t)(bn + r0) * cD + c0);
  bN1 = *(const short8*)(W + (size_t)(bn + r1) * cD + c1);
  *(short8*)&As[0][r0][c0] = aN0;
  *(short8*)&As[0][r1][c1] = aN1;
  *(short8*)&Bs[0][r0][c0] = bN0;
  *(short8*)&Bs[0][r1][c1] = bN1;
  __syncthreads();

  f32x4 acc[4][4] = {};
  int cb = 0;
  for (int kt = 0; kt < cD; kt += 32) {
    const int ktn = kt + 32;
    const bool hn = ktn < cD;
    if (hn) {
      aN0 = *(const short8*)(A + (size_t)(bm + r0) * cD + ktn + c0);
      aN1 = *(const short8*)(A + (size_t)(bm + r1) * cD + ktn + c1);
      bN0 = *(const short8*)(W + (size_t)(bn + r0) * cD + ktn + c0);
      bN1 = *(const short8*)(W + (size_t)(bn + r1) * cD + ktn + c1);
    }
    short8 af[4], bfv[4];
#pragma unroll
    for (int m = 0; m < 4; ++m) af[m] = *(const short8*)&As[cb][wr * 64 + m * 16 + fr][fg * 8];
#pragma unroll
    for (int n = 0; n < 4; ++n) bfv[n] = *(const short8*)&Bs[cb][wc * 64 + n * 16 + fr][fg * 8];
#pragma unroll
    for (int m = 0; m < 4; ++m)
#pragma unroll
      for (int n = 0; n < 4; ++n)
        acc[m][n] = __builtin_amdgcn_mfma_f32_16x16x32_bf16(af[m], bfv[n], acc[m][n], 0, 0, 0);
    if (hn) {
      *(short8*)&As[cb ^ 1][r0][c0] = aN0;
      *(short8*)&As[cb ^ 1][r1][c1] = aN1;
      *(short8*)&Bs[cb ^ 1][r0][c0] = bN0;
      *(short8*)&Bs[cb ^ 1][r1][c1] = bN1;
    }
    __syncthreads();
    cb ^= 1;
  }
#pragma unroll
  for (int m = 0; m < 4; ++m)
#pragma unroll
    for (int n = 0; n < 4; ++n)
#pragma unroll
      for (int r = 0; r < 4; ++r) {
        int row = bm + wr * 64 + m * 16 + fg * 4 + r;
        int col = bn + wc * 64 + n * 16 + fr;
        C[(size_t)row * cV + col] = 30.f * tanhf(acc[m][n][r] * (1.f / 30.f));
      }
}

} // namespace

// ---------------- launch ----------------

extern "C" void kernel_launch(void* const* d_in, const int* in_sizes, int n_in,
                              void* d_out, int out_size, void* d_ws, size_t ws_size,
                              hipStream_t stream) {
  const int*   tokens    = (const int*)d_in[0];
  const float* embed_w   = (const float*)d_in[1];
  const float* ve_w      = (const float*)d_in[2];
  const float* lm_head_w = (const float*)d_in[3];
  const float* in_wq  = (const float*)d_in[4];
  const float* in_wk  = (const float*)d_in[5];
  const float* in_wv  = (const float*)d_in[6];
  const float* in_wo  = (const float*)d_in[7];
  const float* in_al  = (const float*)d_in[8];
  const float* in_fc  = (const float*)d_in[9];
  const float* in_pr  = (const float*)d_in[10];
  const float* in_lam = (const float*)d_in[11];
  const float* mid_wq = (const float*)d_in[12];
  const float* mid_wk = (const float*)d_in[13];
  const float* mid_wv = (const float*)d_in[14];
  const float* mid_wo = (const float*)d_in[15];
  const float* mid_al = (const float*)d_in[16];
  const float* mid_fc = (const float*)d_in[17];
  const float* mid_pr = (const float*)d_in[18];
  const float* router_w = (const float*)d_in[19];
  const float* router_b = (const float*)d_in[20];
  const float* out_wq = (const float*)d_in[21];
  const float* out_wk = (const float*)d_in[22];
  const float* out_wv = (const float*)d_in[23];
  const float* out_wo = (const float*)d_in[24];
  const float* out_al = (const float*)d_in[25];
  const float* out_fc = (const float*)d_in[26];
  const float* out_pr = (const float*)d_in[27];
  const float* out_lam = (const float*)d_in[28];
  const float* gumbel_u = (const float*)d_in[29];
  const int*   wbp  = (const int*)d_in[30];
  const int*   mbcp = (const int*)d_in[31];
  float* outp = (float*)d_out;

  float* ws = (float*)d_ws;
  float* xb   = ws;
  float* x0b  = xb  + cTD;
  float* veb  = x0b + cTD;
  float* yb   = veb + cTD;
  float* cosb = yb  + cTD;
  float* sinb = cosb + cT * 48;
  float* rsum = sinb + cT * 48;           // 1024
  float* feat = rsum + 1024;              // 768 (+pad)
  int*   curp  = (int*)(feat + 784);
  int*   donep = curp + 1;
  float* cntp  = (float*)(curp + 2);
  short* xnbf  = (short*)(feat + 784 + 8);   // T*D bf16
  short* aobf  = xnbf + cTD;                 // also pr-partial z=0
  short* qbf   = aobf + cTD;                 // z=1
  short* kbf   = qbf  + cTD;                 // z=2
  short* vbf   = kbf  + cTD;                 // z=3
  short* pbuf  = aobf;
  short* hidbf = vbf  + cTD;                 // T*Dff bf16
  short* slot0 = hidbf + (size_t)cT * cDff;  // weight slots
  short* slot1 = slot0 + cWTOT;
  short* lmw   = slot1 + cWTOT;

  const dim3 gFix(cConvBlocks + cT, 1, 1);
  const dim3 gEmbed(cT + cConvBlocks, 1, 1);
  const dim3 gQKV(cH, cT / 64, 3);
  const dim3 gWO(cD / 64, cT / 64, 1);
  const dim3 gPR(cD / 64, cT / 64, 4);
  const dim3 gFF(cDff / 128, cT / 64, 1);
  const dim3 gLM(2000, 1, 1);
  const dim3 gAttn(cT / 64, cH, 1);
  const dim3 gRedC(cD / 32 + 432, 8, 1);      // reduce + slot convert (432*8=3456)
  const dim3 gRedLM(cD / 32 + 1500, 8, 1);    // reduce + lm convert (1500*8=12000)

  auto body = [&](const short* slot, const int* cur, const int* done,
                  float* xin, float* yout, const float* vept) {
    qkv_k<<<gQKV, 256, 0, stream>>>(xnbf, slot, qbf, kbf, vbf, done,
                                    cur ? mid_al : (vept ? (xin == xb && yout == xb && vept ? in_al : in_al) : in_al),
                                    cur, vept, cosb, sinb);
    attn_f<<<gAttn, 256, 0, stream>>>(qbf, kbf, vbf, aobf, wbp, done);
    gemm64_k<1, float><<<gWO, 256, 0, stream>>>(aobf, slot + oWO, yout, done, xin, rsum,
                                                cD, cD, cD);
    mgemm_fc_k<<<gFF, 256, 0, stream>>>(yout, rsum, slot + oFC, hidbf, done, cD, cDff);
    gemm64_k<4, short><<<gPR, 256, 0, stream>>>(hidbf, slot + oPR, pbuf, done, nullptr,
                                                nullptr, cDff, cDff / 4, cD);
  };
  (void)body;

  init_state_k<<<1, 256, 0, stream>>>(curp, donep, cntp, feat);
  rope_pre_k<<<(cT * 48 + 255) / 256, 256, 0, stream>>>(cosb, sinb);
  // embed + convert IN weights -> slot1
  embed_rms_k<<<gEmbed, 256, 0, stream>>>(tokens, embed_w, ve_w, x0b, veb,
                                          in_wq, in_wk, in_wv, in_wo, in_fc, in_pr, slot1);

  // ---- in layer (weights in slot1) ----
  axpy_lam_k<<<cTD / 256, 256, 0, stream>>>(in_lam, x0b, x0b, xb, cTD);
  rms_pre_k<<<cT, 256, 0, stream>>>(xb, xnbf, rsum, nullptr);
  qkv_k<<<gQKV, 256, 0, stream>>>(xnbf, slot1, qbf, kbf, vbf, nullptr, in_al,
                                  nullptr, veb, cosb, sinb);
  attn_f<<<gAttn, 256, 0, stream>>>(qbf, kbf, vbf, aobf, wbp, nullptr);
  gemm64_k<1, float><<<gWO, 256, 0, stream>>>(aobf, slot1 + oWO, xb, nullptr, xb, rsum,
                                              cD, cD, cD);
  mgemm_fc_k<<<gFF, 256, 0, stream>>>(xb, rsum, slot1 + oFC, hidbf, nullptr, cD, cDff);
  gemm64_k<4, short><<<gPR, 256, 0, stream>>>(hidbf, slot1 + oPR, pbuf, nullptr, nullptr,
                                              nullptr, cDff, cDff / 4, cD);
  // reduce + speculative convert of expert 0 -> slot0 (always)
  reduce_k<<<gRedC, 256, 0, stream>>>(pbuf, xb, nullptr, nullptr, nullptr,
                                      mid_wq, mid_wk, mid_wv, mid_wo, mid_fc, mid_pr,
                                      nullptr, 0L, slot0, 0, 1);

  // ---- routed mid layers ----
  for (int it = 0; it < cM; ++it) {
    short* slot  = (it & 1) ? slot1 : slot0;
    short* nslot = (it & 1) ? slot0 : slot1;
    fix_pre_k<<<gFix, 256, 0, stream>>>(mid_wq, mid_wk, mid_wv, mid_wo, mid_fc, mid_pr,
                                        slot, curp, donep, it, xb, xnbf, rsum);
    qkv_k<<<gQKV, 256, 0, stream>>>(xnbf, slot, qbf, kbf, vbf, donep, mid_al,
                                    curp, nullptr, cosb, sinb);
    attn_f<<<gAttn, 256, 0, stream>>>(qbf, kbf, vbf, aobf, wbp, donep);
    gemm64_k<1, float><<<gWO, 256, 0, stream>>>(aobf, slot + oWO, yb, donep, xb, rsum,
                                                cD, cD, cD);
    mgemm_fc_k<<<gFF, 256, 0, stream>>>(yb, rsum, slot + oFC, hidbf, donep, cD, cDff);
    gemm64_k<4, short><<<gPR, 256, 0, stream>>>(hidbf, slot + oPR, pbuf, donep, nullptr,
                                                nullptr, cDff, cDff / 4, cD);
    if (it < cM - 1) {
      // speculative convert of expert it+1 -> other slot (gated on done)
      reduce_k<<<gRedC, 256, 0, stream>>>(pbuf, yb, xb, feat, donep,
                                          mid_wq, mid_wk, mid_wv, mid_wo, mid_fc, mid_pr,
                                          nullptr, (long)(it + 1), nslot, 0, 0);
    } else {
      // convert OUT weights -> slot0 (ungated; out layer always runs)
      reduce_k<<<gRedC, 256, 0, stream>>>(pbuf, yb, xb, feat, donep,
                                          out_wq, out_wk, out_wv, out_wo, out_fc, out_pr,
                                          nullptr, 0L, slot0, 0, 1);
    }
    router_step_k<<<1, 64, 0, stream>>>(feat, router_w, router_b, gumbel_u, it, mbcp,
                                        curp, donep, cntp);
  }

  // ---- out layer (weights in slot0) ----
  axpy_lam_k<<<cTD / 256, 256, 0, stream>>>(out_lam, xb, x0b, xb, cTD);
  rms_pre_k<<<cT, 256, 0, stream>>>(xb, xnbf, rsum, nullptr);
  qkv_k<<<gQKV, 256, 0, stream>>>(xnbf, slot0, qbf, kbf, vbf, nullptr, out_al,
                                  nullptr, veb, cosb, sinb);
  attn_f<<<gAttn, 256, 0, stream>>>(qbf, kbf, vbf, aobf, wbp, nullptr);
  gemm64_k<1, float><<<gWO, 256, 0, stream>>>(aobf, slot0 + oWO, xb, nullptr, xb, rsum,
                                              cD, cD, cD);
  mgemm_fc_k<<<gFF, 256, 0, stream>>>(xb, rsum, slot0 + oFC, hidbf, nullptr, cD, cDff);
  gemm64_k<4, short><<<gPR, 256, 0, stream>>>(hidbf, slot0 + oPR, pbuf, nullptr, nullptr,
                                              nullptr, cDff, cDff / 4, cD);
  // reduce + lm weight conversion -> lmw (ungated)
  reduce_k<<<gRedLM, 256, 0, stream>>>(pbuf, xb, nullptr, nullptr, nullptr,
                                       nullptr, nullptr, nullptr, nullptr, nullptr, nullptr,
                                       lm_head_w, 0L, lmw, 1, 1);

  // lm head
  rms_rows_bf<<<cT, 256, 0, stream>>>(xb, xnbf, nullptr);
  gemm_lm_k<<<gLM, 256, 0, stream>>>(xnbf, lmw, outp);
}

// Round 17
// 2125.660 us; speedup vs baseline: 1.0150x; 1.0150x over previous
//
#include <hip/hip_runtime.h>
#include <hip/hip_bf16.h>

namespace {

constexpr int cT   = 1024;
constexpr int cD   = 768;
constexpr int cH   = 8;
constexpr int cHD  = 96;
constexpr int cM   = 10;
constexpr int cDff = 3072;
constexpr int cV   = 32000;
constexpr int cTD  = cT * cD;
constexpr float cEps = 1e-6f;

// wbf element offsets
constexpr long oWQ = 0;
constexpr long oWK = 589824;
constexpr long oWV = 2L * 589824;
constexpr long oWO = 3L * 589824;
constexpr long oFC = 4L * 589824;
constexpr long oPR = 4L * 589824 + 2359296;
constexpr long cWTOT = 4L * 589824 + 2L * 2359296;   // 7077888
constexpr int cConvBlocks = (int)(cWTOT / 8 / 256);  // 3456

typedef __attribute__((ext_vector_type(8))) short short8;
typedef __attribute__((ext_vector_type(4))) float f32x4;

__device__ inline short bf16r(float f) {
  union { float f; unsigned u; } x{f};
  unsigned r = (x.u + 0x7FFF + ((x.u >> 16) & 1)) >> 16;
  return (short)r;
}

__device__ inline float bf2f(short s) {
  union { unsigned u; float f; } x;
  x.u = ((unsigned)(unsigned short)s) << 16;
  return x.f;
}

// ---------------- state / misc ----------------

__global__ void init_state_k(int* cur, int* done, float* cnt, float* feat) {
  if (threadIdx.x == 0) { *cur = 0; *done = 0; *cnt = 0.0f; }
  for (int d = threadIdx.x; d < cD; d += 256) feat[d] = 0.f;
}

__global__ void rope_pre_k(float* __restrict__ cosb, float* __restrict__ sinb) {
  int idx = blockIdx.x * blockDim.x + threadIdx.x;
  if (idx >= cT * 48) return;
  int t = idx / 48, j = idx % 48;
  float th = 0.0f;
  if (j < 24) th = (float)t * powf(1.0f / 1024.0f, (float)j / 23.0f);
  cosb[idx] = cosf(th);
  sinb[idx] = sinf(th);
}

__global__ __launch_bounds__(256) void embed_rms_k(const int* __restrict__ tok,
    const float* __restrict__ ew, const float* __restrict__ vw,
    float* __restrict__ x0, float* __restrict__ ve) {
  int t = blockIdx.x;
  int tk = tok[t];
  const float* er = ew + (size_t)tk * cD;
  const float* vr = vw + (size_t)tk * cD;
  __shared__ float red[256];
  float s = 0.f;
  for (int d = threadIdx.x; d < cD; d += 256) { float e = er[d]; s += e * e; }
  red[threadIdx.x] = s; __syncthreads();
  for (int st = 128; st; st >>= 1) { if (threadIdx.x < st) red[threadIdx.x] += red[threadIdx.x + st]; __syncthreads(); }
  float sc = rsqrtf(red[0] / cD + cEps);
  for (int d = threadIdx.x; d < cD; d += 256) {
    x0[(size_t)t * cD + d] = er[d] * sc;
    ve[(size_t)t * cD + d] = vr[d];
  }
}

// rms over rows -> bf16 output (used pre-lm_head)
__global__ __launch_bounds__(256) void rms_rows_bf(const float* __restrict__ in,
    short* __restrict__ out, const int* done) {
  if (done && *done) return;
  int t = blockIdx.x;
  const float* r = in + (size_t)t * cD;
  __shared__ float red[256];
  float s = 0.f;
  for (int d = threadIdx.x; d < cD; d += 256) { float v = r[d]; s += v * v; }
  red[threadIdx.x] = s; __syncthreads();
  for (int st = 128; st; st >>= 1) { if (threadIdx.x < st) red[threadIdx.x] += red[threadIdx.x + st]; __syncthreads(); }
  float sc = rsqrtf(red[0] / cD + cEps);
  short* o = out + (size_t)t * cD;
  for (int d = threadIdx.x; d < cD; d += 256) o[d] = bf16r(r[d] * sc);
}

__global__ void axpy_lam_k(const float* __restrict__ lam, const float* __restrict__ a,
                           const float* __restrict__ b, float* __restrict__ o, int n) {
  int i = blockIdx.x * 256 + threadIdx.x;
  if (i < n) o[i] = lam[0] * a[i] + lam[1] * b[i];
}

// ---------------- layer_pre: weight convert + rms(xin)->bf16 + rsum zero -----------

__global__ __launch_bounds__(256) void layer_pre_k(const float* __restrict__ s0,
    const float* __restrict__ s1, const float* __restrict__ s2, const float* __restrict__ s3,
    const float* __restrict__ s4, const float* __restrict__ s5, short* __restrict__ dst,
    const int* __restrict__ cur, const int* __restrict__ done,
    const float* __restrict__ xin, short* __restrict__ xnbf, float* __restrict__ rsum) {
  if (done && *done) return;
  const int b = blockIdx.x;
  if (b < cConvBlocks) {
    long e = ((long)b * 256 + threadIdx.x) * 8;
    long cu = cur ? (long)(*cur) : 0L;
    const float* src;
    if (e < oWK)      src = s0 + cu * 589824  + e;
    else if (e < oWV) src = s1 + cu * 589824  + (e - oWK);
    else if (e < oWO) src = s2 + cu * 589824  + (e - oWV);
    else if (e < oFC) src = s3 + cu * 589824  + (e - oWO);
    else if (e < oPR) src = s4 + cu * 2359296 + (e - oFC);
    else              src = s5 + cu * 2359296 + (e - oPR);
    float4 a0 = *(const float4*)src;
    float4 a1 = *(const float4*)(src + 4);
    short8 sv;
    sv[0]=bf16r(a0.x); sv[1]=bf16r(a0.y); sv[2]=bf16r(a0.z); sv[3]=bf16r(a0.w);
    sv[4]=bf16r(a1.x); sv[5]=bf16r(a1.y); sv[6]=bf16r(a1.z); sv[7]=bf16r(a1.w);
    *(short8*)(dst + e) = sv;
  } else {
    const int t = b - cConvBlocks;
    const float* r = xin + (size_t)t * cD;
    __shared__ float red[256];
    float s = 0.f;
    for (int d = threadIdx.x; d < cD; d += 256) { float v = r[d]; s += v * v; }
    red[threadIdx.x] = s; __syncthreads();
    for (int st = 128; st; st >>= 1) { if (threadIdx.x < st) red[threadIdx.x] += red[threadIdx.x + st]; __syncthreads(); }
    float sc = rsqrtf(red[0] / cD + cEps);
    short* o = xnbf + (size_t)t * cD;
    for (int d = threadIdx.x; d < cD; d += 256) o[d] = bf16r(r[d] * sc);
    if (threadIdx.x == 0) rsum[t] = 0.f;
  }
}

__global__ __launch_bounds__(256) void conv1_k(const float* __restrict__ src,
    short* __restrict__ dst, long nchunk) {
  long i = (long)blockIdx.x * 256 + threadIdx.x;
  if (i >= nchunk) return;
  long e = i * 8;
  float4 a0 = *(const float4*)(src + e);
  float4 a1 = *(const float4*)(src + e + 4);
  short8 sv;
  sv[0]=bf16r(a0.x); sv[1]=bf16r(a0.y); sv[2]=bf16r(a0.z); sv[3]=bf16r(a0.w);
  sv[4]=bf16r(a1.x); sv[5]=bf16r(a1.y); sv[6]=bf16r(a1.z); sv[7]=bf16r(a1.w);
  *(short8*)(dst + e) = sv;
}

// ---------------- QKV GEMM with fused per-head RMS + RoPE / lam-scale -------------
// 64x96 tile (one head per block), 4 waves stacked on M; double-buffered staging.

__global__ __launch_bounds__(256) void qkv_k(const short* __restrict__ A,
    const short* __restrict__ Wb,
    short* __restrict__ qo, short* __restrict__ ko, short* __restrict__ vo,
    const int* __restrict__ done, const float* __restrict__ lamb,
    const int* __restrict__ cur, const float* __restrict__ vep,
    const float* __restrict__ cosb, const float* __restrict__ sinb) {
  if (done && *done) return;
  const int z = blockIdx.z;
  const short* W = Wb + (long)z * 589824L;
  const int h  = blockIdx.x;
  const int bm = blockIdx.y * 64;
  __shared__ short As[2][64][40];
  __shared__ short Bs[2][96][40];
  const int tid = threadIdx.x;
  const int w = tid >> 6, lane = tid & 63;
  const int fr = lane & 15, fg = lane >> 4;
  const int ar = tid >> 2, ac2 = (tid & 3) << 3;
  const int br1 = (256 + tid) >> 2, bc1 = ((256 + tid) & 3) << 3;

  short8 aN, bN0, bN1;
  aN  = *(const short8*)(A + (size_t)(bm + ar) * cD + ac2);
  bN0 = *(const short8*)(W + (size_t)(h * cHD + ar) * cD + ac2);
  if (tid < 128) bN1 = *(const short8*)(W + (size_t)(h * cHD + br1) * cD + bc1);
  *(short8*)&As[0][ar][ac2] = aN;
  *(short8*)&Bs[0][ar][ac2] = bN0;
  if (tid < 128) *(short8*)&Bs[0][br1][bc1] = bN1;
  __syncthreads();

  f32x4 acc[6] = {};
  int cb = 0;
  for (int kt = 0; kt < cD; kt += 32) {
    const int ktn = kt + 32;
    const bool hn = ktn < cD;
    if (hn) {
      aN  = *(const short8*)(A + (size_t)(bm + ar) * cD + ktn + ac2);
      bN0 = *(const short8*)(W + (size_t)(h * cHD + ar) * cD + ktn + ac2);
      if (tid < 128) bN1 = *(const short8*)(W + (size_t)(h * cHD + br1) * cD + ktn + bc1);
    }
    short8 af = *(const short8*)&As[cb][w * 16 + fr][fg * 8];
#pragma unroll
    for (int n = 0; n < 6; ++n) {
      short8 bf = *(const short8*)&Bs[cb][n * 16 + fr][fg * 8];
      acc[n] = __builtin_amdgcn_mfma_f32_16x16x32_bf16(af, bf, acc[n], 0, 0, 0);
    }
    if (hn) {
      *(short8*)&As[cb ^ 1][ar][ac2] = aN;
      *(short8*)&Bs[cb ^ 1][ar][ac2] = bN0;
      if (tid < 128) *(short8*)&Bs[cb ^ 1][br1][bc1] = bN1;
    }
    __syncthreads();
    cb ^= 1;
  }

  const int t0 = bm + w * 16 + fg * 4;
  if (z < 2) {
    float scl[4];
#pragma unroll
    for (int r = 0; r < 4; ++r) {
      float s = 0.f;
#pragma unroll
      for (int n = 0; n < 6; ++n) s += acc[n][r] * acc[n][r];
#pragma unroll
      for (int mm = 1; mm < 16; mm <<= 1) s += __shfl_xor(s, mm, 64);
      scl[r] = rsqrtf(s * (1.0f / 96.0f) + cEps);
    }
    short* C = (z == 0 ? qo : ko);
#pragma unroll
    for (int r = 0; r < 4; ++r) {
      int t = t0 + r;
      short* orow = C + (size_t)t * cD + h * cHD;
#pragma unroll
      for (int n = 0; n < 3; ++n) {
        int j = n * 16 + fr;
        float c = cosb[t * 48 + j], sn = sinb[t * 48 + j];
        float x1 = acc[n][r] * scl[r], x2 = acc[n + 3][r] * scl[r];
        orow[j]      = bf16r(x1 * c + x2 * sn);
        orow[j + 48] = bf16r(-x1 * sn + x2 * c);
      }
    }
  } else {
    int cu = cur ? *cur : 0;
    float l0 = lamb[2 * cu], l1 = lamb[2 * cu + 1];
#pragma unroll
    for (int r = 0; r < 4; ++r) {
      int t = t0 + r;
#pragma unroll
      for (int n = 0; n < 6; ++n) {
        float val = l0 * acc[n][r];
        if (vep) val += l1 * vep[(size_t)t * cD + h * cHD + n * 16 + fr];
        vo[(size_t)t * cD + h * cHD + n * 16 + fr] = bf16r(val);
      }
    }
  }
}

// ---------------- flash attention (windowed causal, bf16 in/out, pipelined) -------

__global__ __launch_bounds__(256) void attn_f(const short* __restrict__ q,
    const short* __restrict__ k, const short* __restrict__ v, short* __restrict__ o,
    const int* __restrict__ wbp, const int* done) {
  if (done && *done) return;
  const int qb = blockIdx.x;
  const int h  = blockIdx.y;
  const int q0 = qb * 64;
  const int qb128 = q0 >> 7;
  const int wb = *wbp;
  int kb_lo = qb128 - wb + 1; if (kb_lo < 0) kb_lo = 0;

  __shared__ short Ksh[128][136];
  __shared__ short Vt[96][136];

  const int tid  = threadIdx.x;
  const int w    = tid >> 6;
  const int lane = tid & 63;
  const int fr   = lane & 15;
  const int fg   = lane >> 4;

  short8 qf[3];
  {
    const short* qrow = q + (size_t)(q0 + w * 16 + fr) * cD + h * cHD;
#pragma unroll
    for (int ks = 0; ks < 3; ++ks) qf[ks] = *(const short8*)(qrow + ks * 32 + fg * 8);
  }

  short8 rK[6], rV[6];
  auto issue = [&](int kb) {
    const int key0 = kb * 128;
#pragma unroll
    for (int c = 0; c < 6; ++c) {
      int idx = c * 256 + tid;
      int row = idx / 12, colc = (idx % 12) * 8;
      rK[c] = *(const short8*)(k + (size_t)(key0 + row) * cD + h * cHD + colc);
      rV[c] = *(const short8*)(v + (size_t)(key0 + row) * cD + h * cHD + colc);
    }
  };

  f32x4 accO[6] = {};
  float mrun[4], lrun[4];
#pragma unroll
  for (int r = 0; r < 4; ++r) { mrun[r] = -1e30f; lrun[r] = 0.f; }

  issue(kb_lo);
  for (int kb = kb_lo; kb <= qb128; ++kb) {
    __syncthreads();
#pragma unroll
    for (int c = 0; c < 6; ++c) {
      int idx = c * 256 + tid;
      int row = idx / 12, colc = (idx % 12) * 8;
      *(short8*)&Ksh[row][colc] = rK[c];
      short8 vv = rV[c];
#pragma unroll
      for (int i = 0; i < 8; ++i) Vt[colc + i][row] = vv[i];
    }
    __syncthreads();
    if (kb < qb128) issue(kb + 1);

    const int key0 = kb * 128;
    f32x4 s[8];
#pragma unroll
    for (int n = 0; n < 8; ++n) s[n] = (f32x4){0.f, 0.f, 0.f, 0.f};
#pragma unroll
    for (int ks = 0; ks < 3; ++ks) {
#pragma unroll
      for (int n = 0; n < 8; ++n) {
        short8 kf = *(const short8*)&Ksh[n * 16 + fr][ks * 32 + fg * 8];
        s[n] = __builtin_amdgcn_mfma_f32_16x16x32_bf16(qf[ks], kf, s[n], 0, 0, 0);
      }
    }

    float pmax[4] = {-1e30f, -1e30f, -1e30f, -1e30f};
#pragma unroll
    for (int n = 0; n < 8; ++n)
#pragma unroll
      for (int r = 0; r < 4; ++r) {
        float val = s[n][r] * 0.10206207261596577f;
        int key  = key0 + n * 16 + fr;
        int qrow = q0 + w * 16 + fg * 4 + r;
        if (key > qrow) val = -1e30f;
        s[n][r] = val;
        pmax[r] = fmaxf(pmax[r], val);
      }
#pragma unroll
    for (int mm = 1; mm < 16; mm <<= 1)
#pragma unroll
      for (int r = 0; r < 4; ++r) pmax[r] = fmaxf(pmax[r], __shfl_xor(pmax[r], mm, 64));
    float alpha[4], psum[4];
#pragma unroll
    for (int r = 0; r < 4; ++r) {
      float mn = fmaxf(mrun[r], pmax[r]);
      alpha[r] = __expf(mrun[r] - mn);
      mrun[r] = mn;
      psum[r] = 0.f;
    }
#pragma unroll
    for (int n = 0; n < 8; ++n)
#pragma unroll
      for (int r = 0; r < 4; ++r) {
        float p = __expf(s[n][r] - mrun[r]);
        s[n][r] = p;
        psum[r] += p;
      }
#pragma unroll
    for (int mm = 1; mm < 16; mm <<= 1)
#pragma unroll
      for (int r = 0; r < 4; ++r) psum[r] += __shfl_xor(psum[r], mm, 64);
#pragma unroll
    for (int r = 0; r < 4; ++r) lrun[r] = lrun[r] * alpha[r] + psum[r];
#pragma unroll
    for (int n = 0; n < 6; ++n) {
      f32x4 t = accO[n];
#pragma unroll
      for (int r = 0; r < 4; ++r) t[r] *= alpha[r];
      accO[n] = t;
    }

    __syncthreads();
#pragma unroll
    for (int n = 0; n < 8; ++n)
#pragma unroll
      for (int r = 0; r < 4; ++r)
        Ksh[w * 16 + fg * 4 + r][n * 16 + fr] = bf16r(s[n][r]);
    __syncthreads();

#pragma unroll
    for (int ks = 0; ks < 4; ++ks) {
      short8 pf = *(const short8*)&Ksh[w * 16 + fr][ks * 32 + fg * 8];
#pragma unroll
      for (int n = 0; n < 6; ++n) {
        short8 vf = *(const short8*)&Vt[n * 16 + fr][ks * 32 + fg * 8];
        accO[n] = __builtin_amdgcn_mfma_f32_16x16x32_bf16(pf, vf, accO[n], 0, 0, 0);
      }
    }
  }

#pragma unroll
  for (int r = 0; r < 4; ++r) {
    float inv = 1.0f / lrun[r];
    int t = q0 + w * 16 + fg * 4 + r;
#pragma unroll
    for (int n = 0; n < 6; ++n)
      o[(size_t)t * cD + h * cHD + n * 16 + fr] = bf16r(accO[n][r] * inv);
  }
}

// ---------------- 64x64-tile GEMM, double-buffered -------------------------------
// EPI 1 (wo): C=fp32 += res, rsum atomics. EPI 4 (pr): bf16 partial per K-chunk z.

template <int EPI, typename OT>
__global__ __launch_bounds__(256) void gemm64_k(const short* __restrict__ A,
    const short* __restrict__ W, OT* __restrict__ C, const int* __restrict__ done,
    const float* __restrict__ res, float* __restrict__ rsum, int ld, int kn, int N) {
  if (done && *done) return;
  const int bm = blockIdx.y * 64;
  const int bn = blockIdx.x * 64;
  const int k0 = blockIdx.z * kn;
  __shared__ short As[2][64][40];
  __shared__ short Bs[2][64][40];
  const int tid = threadIdx.x;
  const int wid = tid >> 6, lane = tid & 63;
  const int wr = wid >> 1, wc = wid & 1;
  const int fr = lane & 15, fg = lane >> 4;
  const int ar = tid >> 2, ac = (tid & 3) << 3;

  short8 aN = *(const short8*)(A + (size_t)(bm + ar) * ld + k0 + ac);
  short8 bN = *(const short8*)(W + (size_t)(bn + ar) * ld + k0 + ac);
  *(short8*)&As[0][ar][ac] = aN;
  *(short8*)&Bs[0][ar][ac] = bN;
  __syncthreads();

  f32x4 acc[2][2] = {};
  int cb = 0;
  for (int kt = 0; kt < kn; kt += 32) {
    const int ktn = kt + 32;
    const bool hn = ktn < kn;
    if (hn) {
      aN = *(const short8*)(A + (size_t)(bm + ar) * ld + k0 + ktn + ac);
      bN = *(const short8*)(W + (size_t)(bn + ar) * ld + k0 + ktn + ac);
    }
    short8 af[2], bfv[2];
#pragma unroll
    for (int m = 0; m < 2; ++m) af[m] = *(const short8*)&As[cb][wr * 32 + m * 16 + fr][fg * 8];
#pragma unroll
    for (int n = 0; n < 2; ++n) bfv[n] = *(const short8*)&Bs[cb][wc * 32 + n * 16 + fr][fg * 8];
#pragma unroll
    for (int m = 0; m < 2; ++m)
#pragma unroll
      for (int n = 0; n < 2; ++n)
        acc[m][n] = __builtin_amdgcn_mfma_f32_16x16x32_bf16(af[m], bfv[n], acc[m][n], 0, 0, 0);
    if (hn) {
      *(short8*)&As[cb ^ 1][ar][ac] = aN;
      *(short8*)&Bs[cb ^ 1][ar][ac] = bN;
    }
    __syncthreads();
    cb ^= 1;
  }
#pragma unroll
  for (int m = 0; m < 2; ++m)
#pragma unroll
    for (int r = 0; r < 4; ++r) {
      const int row = bm + wr * 32 + m * 16 + fg * 4 + r;
      float p = 0.f;
#pragma unroll
      for (int n = 0; n < 2; ++n) {
        const int col = bn + wc * 32 + n * 16 + fr;
        float val = acc[m][n][r];
        if constexpr (EPI == 1) {
          val += res[(size_t)row * N + col];
          C[(size_t)row * N + col] = val;
          p += val * val;
        } else {
          C[(size_t)blockIdx.z * cTD + (size_t)row * N + col] = (OT)bf16r(val);
        }
      }
      if constexpr (EPI == 1) {
#pragma unroll
        for (int mm = 1; mm < 16; mm <<= 1) p += __shfl_xor(p, mm, 64);
        if (fr == 0) atomicAdd(&rsum[row], p);
      }
    }
}

// ---------------- fc GEMM: 64x64 tile (768 blocks), fused RMS on A -----------------

__global__ __launch_bounds__(256) void mgemm_fc_k(const float* __restrict__ Ay,
    const float* __restrict__ rsum, const short* __restrict__ W, short* __restrict__ C,
    const int* __restrict__ done, int K, int N) {
  if (done && *done) return;
  const int bm = blockIdx.y * 64;
  const int bn = blockIdx.x * 64;
  __shared__ short As[2][64][40];
  __shared__ short Bs[2][64][40];
  const int tid = threadIdx.x;
  const int wid = tid >> 6, lane = tid & 63;
  const int wr = wid >> 1, wc = wid & 1;
  const int fr = lane & 15, fg = lane >> 4;
  const int ar = tid >> 2, ac = (tid & 3) << 3;

  const float ascl = rsqrtf(rsum[bm + ar] * (1.0f / cD) + cEps);
  const float* arow = Ay + (size_t)(bm + ar) * K;

  auto loadA = [&](int kt) -> short8 {
    float4 a0 = *(const float4*)(arow + kt + ac);
    float4 a1 = *(const float4*)(arow + kt + ac + 4);
    short8 sv;
    sv[0]=bf16r(a0.x*ascl); sv[1]=bf16r(a0.y*ascl); sv[2]=bf16r(a0.z*ascl); sv[3]=bf16r(a0.w*ascl);
    sv[4]=bf16r(a1.x*ascl); sv[5]=bf16r(a1.y*ascl); sv[6]=bf16r(a1.z*ascl); sv[7]=bf16r(a1.w*ascl);
    return sv;
  };

  short8 aN = loadA(0);
  short8 bN = *(const short8*)(W + (size_t)(bn + ar) * K + ac);
  *(short8*)&As[0][ar][ac] = aN;
  *(short8*)&Bs[0][ar][ac] = bN;
  __syncthreads();

  f32x4 acc[2][2] = {};
  int cb = 0;
  for (int kt = 0; kt < K; kt += 32) {
    const int ktn = kt + 32;
    const bool hn = ktn < K;
    if (hn) {
      aN = loadA(ktn);
      bN = *(const short8*)(W + (size_t)(bn + ar) * K + ktn + ac);
    }
    short8 af[2], bfv[2];
#pragma unroll
    for (int m = 0; m < 2; ++m) af[m] = *(const short8*)&As[cb][wr * 32 + m * 16 + fr][fg * 8];
#pragma unroll
    for (int n = 0; n < 2; ++n) bfv[n] = *(const short8*)&Bs[cb][wc * 32 + n * 16 + fr][fg * 8];
#pragma unroll
    for (int m = 0; m < 2; ++m)
#pragma unroll
      for (int n = 0; n < 2; ++n)
        acc[m][n] = __builtin_amdgcn_mfma_f32_16x16x32_bf16(af[m], bfv[n], acc[m][n], 0, 0, 0);
    if (hn) {
      *(short8*)&As[cb ^ 1][ar][ac] = aN;
      *(short8*)&Bs[cb ^ 1][ar][ac] = bN;
    }
    __syncthreads();
    cb ^= 1;
  }
#pragma unroll
  for (int m = 0; m < 2; ++m)
#pragma unroll
    for (int n = 0; n < 2; ++n)
#pragma unroll
      for (int r = 0; r < 4; ++r) {
        int row = bm + wr * 32 + m * 16 + fg * 4 + r;
        int col = bn + wc * 32 + n * 16 + fr;
        float val = acc[m][n][r];
        val = fmaxf(val, 0.f); val = val * val;
        C[(size_t)row * N + col] = bf16r(val);
      }
}

// ---------------- split-K reduce + residual + commit + feat (atomic partial) -------

__global__ __launch_bounds__(256) void reduce_k(const short* __restrict__ pb,
    float* __restrict__ y, float* __restrict__ x, float* __restrict__ feat,
    const int* done) {
  if (done && *done) return;
  __shared__ float red[256];
  const int d = blockIdx.x * 32 + (threadIdx.x & 31);
  const int tc = threadIdx.x >> 5;
  const int t0 = blockIdx.y * 128 + tc * 16;
  float s = 0.f;
  for (int t = t0; t < t0 + 16; ++t) {
    size_t i = (size_t)t * cD + d;
    float v = y[i];
#pragma unroll
    for (int z = 0; z < 4; ++z) v += bf2f(pb[(size_t)z * cTD + i]);
    y[i] = v;
    if (x) x[i] = v;
    s += v;
  }
  if (feat) {
    red[threadIdx.x] = s; __syncthreads();
    if (threadIdx.x < 32) {
      float tot = 0.f;
#pragma unroll
      for (int c = 0; c < 8; ++c) tot += red[c * 32 + threadIdx.x];
      atomicAdd(&feat[d], tot * (1.0f / cT));
    }
  }
}

// ---------------- router (single block; zeroes feat for next iteration) ------------

__global__ void router_step_k(float* __restrict__ feat, const float* __restrict__ rw,
    const float* __restrict__ rb, const float* __restrict__ gu, int iter,
    const int* __restrict__ mbcp, int* cur, int* done, float* cnt) {
  if (*done) return;
  __shared__ float lg[cM + 1];
  const int tid = threadIdx.x;   // 64 threads
  const int c = *cur;
  const float mbc = (float)(*mbcp);
  const float cn = *cnt;
  for (int j = 0; j < cM + 1; ++j) {
    const float* w = rw + ((size_t)c * (cM + 1) + j) * (cD + 2);
    float s = 0.f;
    for (int d = tid; d < cD; d += 64) s += feat[d] * w[d];
#pragma unroll
    for (int mm = 32; mm; mm >>= 1) s += __shfl_xor(s, mm, 64);
    if (tid == 0) {
      s += cn * w[cD] + mbc * w[cD + 1] + rb[c * (cM + 1) + j];
      float u = gu[iter * (cM + 1) + j];
      float inner = -logf(u + 1e-10f) + 1e-10f;
      lg[j] = s - logf(inner);
    }
  }
  __syncthreads();
  for (int d = tid; d < cD; d += 64) feat[d] = 0.f;
  if (tid == 0) {
    int nxt = 0; float best = lg[0];
    for (int j = 1; j < cM + 1; ++j) if (lg[j] > best) { best = lg[j]; nxt = j; }
    float nc = cn + 1.0f;
    int ex = (nxt == cM) || (nc >= mbc);
    *cnt = nc;
    if (ex) *done = 1; else *cur = nxt;
  }
}

// ---------------- lm_head GEMM: 128x128 tile, 256 threads, dbuf, XCD swizzle --------

__global__ __launch_bounds__(256) void gemm_lm_k(const short* __restrict__ A,
    const short* __restrict__ W, float* __restrict__ C) {
  const int nwg = (cV / 128) * (cT / 128);        // 2000
  const int cpx = nwg / 8;                        // 250
  const int swz = (blockIdx.x % 8) * cpx + blockIdx.x / 8;
  const int bm = (swz & 7) * 128;
  const int bn = (swz >> 3) * 128;
  __shared__ short As[2][128][40];
  __shared__ short Bs[2][128][40];
  const int tid = threadIdx.x;
  const int wid = tid >> 6, lane = tid & 63;
  const int wr = wid >> 1, wc = wid & 1;
  const int fr = lane & 15, fg = lane >> 4;
  const int r0 = tid >> 2, c0 = (tid & 3) << 3;
  const int r1 = (256 + tid) >> 2, c1 = ((256 + tid) & 3) << 3;

  short8 aN0, aN1, bN0, bN1;
  aN0 = *(const short8*)(A + (size_t)(bm + r0) * cD + c0);
  aN1 = *(const short8*)(A + (size_t)(bm + r1) * cD + c1);
  bN0 = *(const short8*)(W + (size_t)(bn + r0) * cD + c0);
  bN1 = *(const short8*)(W + (size_t)(bn + r1) * cD + c1);
  *(short8*)&As[0][r0][c0] = aN0;
  *(short8*)&As[0][r1][c1] = aN1;
  *(short8*)&Bs[0][r0][c0] = bN0;
  *(short8*)&Bs[0][r1][c1] = bN1;
  __syncthreads();

  f32x4 acc[4][4] = {};
  int cb = 0;
  for (int kt = 0; kt < cD; kt += 32) {
    const int ktn = kt + 32;
    const bool hn = ktn < cD;
    if (hn) {
      aN0 = *(const short8*)(A + (size_t)(bm + r0) * cD + ktn + c0);
      aN1 = *(const short8*)(A + (size_t)(bm + r1) * cD + ktn + c1);
      bN0 = *(const short8*)(W + (size_t)(bn + r0) * cD + ktn + c0);
      bN1 = *(const short8*)(W + (size_t)(bn + r1) * cD + ktn + c1);
    }
    short8 af[4], bfv[4];
#pragma unroll
    for (int m = 0; m < 4; ++m) af[m] = *(const short8*)&As[cb][wr * 64 + m * 16 + fr][fg * 8];
#pragma unroll
    for (int n = 0; n < 4; ++n) bfv[n] = *(const short8*)&Bs[cb][wc * 64 + n * 16 + fr][fg * 8];
#pragma unroll
    for (int m = 0; m < 4; ++m)
#pragma unroll
      for (int n = 0; n < 4; ++n)
        acc[m][n] = __builtin_amdgcn_mfma_f32_16x16x32_bf16(af[m], bfv[n], acc[m][n], 0, 0, 0);
    if (hn) {
      *(short8*)&As[cb ^ 1][r0][c0] = aN0;
      *(short8*)&As[cb ^ 1][r1][c1] = aN1;
      *(short8*)&Bs[cb ^ 1][r0][c0] = bN0;
      *(short8*)&Bs[cb ^ 1][r1][c1] = bN1;
    }
    __syncthreads();
    cb ^= 1;
  }
#pragma unroll
  for (int m = 0; m < 4; ++m)
#pragma unroll
    for (int n = 0; n < 4; ++n)
#pragma unroll
      for (int r = 0; r < 4; ++r) {
        int row = bm + wr * 64 + m * 16 + fg * 4 + r;
        int col = bn + wc * 64 + n * 16 + fr;
        C[(size_t)row * cV + col] = 30.f * tanhf(acc[m][n][r] * (1.f / 30.f));
      }
}

} // namespace

// ---------------- launch ----------------

extern "C" void kernel_launch(void* const* d_in, const int* in_sizes, int n_in,
                              void* d_out, int out_size, void* d_ws, size_t ws_size,
                              hipStream_t stream) {
  const int*   tokens    = (const int*)d_in[0];
  const float* embed_w   = (const float*)d_in[1];
  const float* ve_w      = (const float*)d_in[2];
  const float* lm_head_w = (const float*)d_in[3];
  const float* in_wq  = (const float*)d_in[4];
  const float* in_wk  = (const float*)d_in[5];
  const float* in_wv  = (const float*)d_in[6];
  const float* in_wo  = (const float*)d_in[7];
  const float* in_al  = (const float*)d_in[8];
  const float* in_fc  = (const float*)d_in[9];
  const float* in_pr  = (const float*)d_in[10];
  const float* in_lam = (const float*)d_in[11];
  const float* mid_wq = (const float*)d_in[12];
  const float* mid_wk = (const float*)d_in[13];
  const float* mid_wv = (const float*)d_in[14];
  const float* mid_wo = (const float*)d_in[15];
  const float* mid_al = (const float*)d_in[16];
  const float* mid_fc = (const float*)d_in[17];
  const float* mid_pr = (const float*)d_in[18];
  const float* router_w = (const float*)d_in[19];
  const float* router_b = (const float*)d_in[20];
  const float* out_wq = (const float*)d_in[21];
  const float* out_wk = (const float*)d_in[22];
  const float* out_wv = (const float*)d_in[23];
  const float* out_wo = (const float*)d_in[24];
  const float* out_al = (const float*)d_in[25];
  const float* out_fc = (const float*)d_in[26];
  const float* out_pr = (const float*)d_in[27];
  const float* out_lam = (const float*)d_in[28];
  const float* gumbel_u = (const float*)d_in[29];
  const int*   wbp  = (const int*)d_in[30];
  const int*   mbcp = (const int*)d_in[31];
  float* outp = (float*)d_out;

  float* ws = (float*)d_ws;
  float* xb   = ws;
  float* x0b  = xb  + cTD;
  float* veb  = x0b + cTD;
  float* yb   = veb + cTD;
  float* cosb = yb  + cTD;
  float* sinb = cosb + cT * 48;
  float* rsum = sinb + cT * 48;           // 1024
  float* feat = rsum + 1024;              // 768 (+pad)
  int*   curp  = (int*)(feat + 784);
  int*   donep = curp + 1;
  float* cntp  = (float*)(curp + 2);
  short* xnbf  = (short*)(feat + 784 + 8);   // T*D bf16
  short* aobf  = xnbf + cTD;                 // also pr-partial z=0
  short* qbf   = aobf + cTD;                 // z=1
  short* kbf   = qbf  + cTD;                 // z=2
  short* vbf   = kbf  + cTD;                 // z=3
  short* pbuf  = aobf;
  short* hidbf = vbf  + cTD;                 // T*Dff bf16
  short* wbf   = hidbf + (size_t)cT * cDff;  // layer weights / lm_head bf16

  const dim3 gPre(cConvBlocks + cT, 1, 1);
  const dim3 gQKV(cH, cT / 64, 3);
  const dim3 gWO(cD / 64, cT / 64, 1);
  const dim3 gPR(cD / 64, cT / 64, 4);
  const dim3 gFF(cDff / 64, cT / 64, 1);             // 48 x 16 = 768 blocks
  const dim3 gLM(2000, 1, 1);
  const dim3 gAttn(cT / 64, cH, 1);
  const dim3 gRed(cD / 32, 8, 1);                    // 192 blocks
  const long lmChunks = (long)cV * cD / 8;           // 3072000
  const int gConvLM = (int)(lmChunks / 256);         // 12000

  auto layer = [&](const float* wq, const float* wk, const float* wv, const float* wo,
                   const float* alam, const float* fc, const float* pr,
                   const int* cur, const int* done,
                   float* xin, float* yout, const float* vept,
                   float* xcom, float* featp) {
    layer_pre_k<<<gPre, 256, 0, stream>>>(wq, wk, wv, wo, fc, pr, wbf, cur, done,
                                          xin, xnbf, rsum);
    qkv_k<<<gQKV, 256, 0, stream>>>(xnbf, wbf, qbf, kbf, vbf, done, alam, cur, vept,
                                    cosb, sinb);
    attn_f<<<gAttn, 256, 0, stream>>>(qbf, kbf, vbf, aobf, wbp, done);
    gemm64_k<1, float><<<gWO, 256, 0, stream>>>(aobf, wbf + oWO, yout, done, xin, rsum,
                                                cD, cD, cD);
    mgemm_fc_k<<<gFF, 256, 0, stream>>>(yout, rsum, wbf + oFC, hidbf, done, cD, cDff);
    gemm64_k<4, short><<<gPR, 256, 0, stream>>>(hidbf, wbf + oPR, pbuf, done, nullptr,
                                                nullptr, cDff, cDff / 4, cD);
    reduce_k<<<gRed, 256, 0, stream>>>(pbuf, yout, xcom, featp, done);
  };

  init_state_k<<<1, 256, 0, stream>>>(curp, donep, cntp, feat);
  rope_pre_k<<<(cT * 48 + 255) / 256, 256, 0, stream>>>(cosb, sinb);
  embed_rms_k<<<cT, 256, 0, stream>>>(tokens, embed_w, ve_w, x0b, veb);

  axpy_lam_k<<<cTD / 256, 256, 0, stream>>>(in_lam, x0b, x0b, xb, cTD);
  layer(in_wq, in_wk, in_wv, in_wo, in_al, in_fc, in_pr, nullptr, nullptr,
        xb, xb, veb, nullptr, nullptr);

  for (int it = 0; it < cM; ++it) {
    layer(mid_wq, mid_wk, mid_wv, mid_wo, mid_al, mid_fc, mid_pr,
          curp, donep, xb, yb, nullptr, xb, feat);
    router_step_k<<<1, 64, 0, stream>>>(feat, router_w, router_b, gumbel_u, it, mbcp,
                                        curp, donep, cntp);
  }

  axpy_lam_k<<<cTD / 256, 256, 0, stream>>>(out_lam, xb, x0b, xb, cTD);
  layer(out_wq, out_wk, out_wv, out_wo, out_al, out_fc, out_pr, nullptr, nullptr,
        xb, xb, veb, nullptr, nullptr);

  // lm head: convert weight once, then bf16 GEMM with tanh soft-cap
  conv1_k<<<gConvLM, 256, 0, stream>>>(lm_head_w, wbf, lmChunks);
  rms_rows_bf<<<cT, 256, 0, stream>>>(xb, xnbf, nullptr);
  gemm_lm_k<<<gLM, 256, 0, stream>>>(xnbf, wbf, outp);
}